// Round 16
// baseline (3045.128 us; speedup 1.0000x reference)
//
#include <hip/hip_runtime.h>

#define BB 4
#define NN 8192
#define PP 2048
#define KNB 16
#define CIN 64
#define COUT 128
#define CH0 1748              // chunk 0 covers FPS rounds [1, CH0)
#define R1 (PP - CH0)         // 300 rounds in chunk 1; tail covers R1 pts/batch

__device__ __forceinline__ float elu(float x) { return x > 0.0f ? x : expm1f(x); }

__device__ __forceinline__ unsigned fkey(float d) {
    unsigned u = __float_as_uint(d);
    unsigned m = (unsigned)((int)u >> 31);
    return u ^ (m | 0x80000000u);
}

// 64-lane max reduce on the VALU pipe via DPP. (HW-verified rounds 9-15)
__device__ __forceinline__ float wave_max_dpp(float v) {
#define DPP_STEP(ctrl)                                                         \
    {                                                                          \
        int x = __float_as_int(v);                                             \
        int y = __builtin_amdgcn_update_dpp(x, x, (ctrl), 0xf, 0xf, false);    \
        v = fmaxf(v, __int_as_float(y));                                       \
    }
    DPP_STEP(0x111) DPP_STEP(0x112) DPP_STEP(0x114)
    DPP_STEP(0x118) DPP_STEP(0x142) DPP_STEP(0x143)
#undef DPP_STEP
    return __int_as_float(__builtin_amdgcn_readlane(__float_as_int(v), 63));
}

__device__ __forceinline__ unsigned wave_min_u32_dpp(unsigned v) {
#define DPP_STEP(ctrl)                                                         \
    {                                                                          \
        int y = __builtin_amdgcn_update_dpp((int)v, (int)v, (ctrl), 0xf, 0xf, false); \
        v = min(v, (unsigned)y);                                               \
    }
    DPP_STEP(0x111) DPP_STEP(0x112) DPP_STEP(0x114)
    DPP_STEP(0x118) DPP_STEP(0x142) DPP_STEP(0x143)
#undef DPP_STEP
    return (unsigned)__builtin_amdgcn_readlane((int)v, 63);
}

struct FpsSmem {
    float spx[NN], spy[NN], spz[NN];
    unsigned long long partk[2][8];
};
struct ConsSmem {
    int kidx[8][16];
    float pl[4][16][3];
    int nidx[4][16];
    float fcat[4][16][96];
    float A1[4][16][32];
    float Xm[4][16][17];
    float X2[4][16][17];
    float X3[4][16][17];
    float fX[4][16][97];
    float dsep[4][192];
};
union Smem { FpsSmem fps; ConsSmem cons; };

#define PREP_BLOCKS 64
#define DENSE_BASE (4 + PREP_BLOCKS)

// ---------------------------------------------------------------------------
// Mega kernel. blocks 0..3: FPS rounds [s0,s1) (state save/restore in ws).
// mode 0 (chunk 0): blocks 4..67 prep, 68..4163 dense.
// mode 1 (chunk 1): blocks 4.. = fused knn+xconv consumers for cons_cnt
//   points/batch finalized by the PREVIOUS launch (stream-ordered).
// Consumer math identical to standalone kernels -> bitwise-identical output.
// ---------------------------------------------------------------------------
__global__ __launch_bounds__(512) void mega_kernel(
    const float* __restrict__ pts, float* __restrict__ rep,
    const float* __restrict__ fts, const float* __restrict__ denseW,
    const float* __restrict__ denseb, float* __restrict__ ftsd,
    const float* __restrict__ convW, const float* __restrict__ dw1W,
    const float* __restrict__ dw2W, const float* __restrict__ sdwW,
    const float* __restrict__ spwW,
    float* __restrict__ convT, float* __restrict__ dw1T, float* __restrict__ dw2T,
    float* __restrict__ sdwT, float* __restrict__ spwT, float* __restrict__ ptsT,
    float* __restrict__ fstate,
    const float* __restrict__ d1W, const float* __restrict__ d1b,
    const float* __restrict__ d2W, const float* __restrict__ d2b,
    const float* __restrict__ convb, const float* __restrict__ dw1b,
    const float* __restrict__ dw2b, const float* __restrict__ sdwb,
    const float* __restrict__ spwb, float* __restrict__ outp,
    int s0, int s1, int mode, int cons_p0, int cons_cnt) {
    const int bid = blockIdx.x;
    const int t = threadIdx.x;

    __shared__ Smem sm;

    if (bid >= 4 && mode == 0) {
        if (bid >= DENSE_BASE) {
            // ---------------- dense: 8 rows/block, one wave per row --------
            const int row = (bid - DENSE_BASE) * 8 + (t >> 6);
            const int c = t & 63;
            float v = fts[(size_t)row * 64 + c];
            float acc = denseb[c];
#pragma unroll 8
            for (int k = 0; k < 64; ++k) acc = fmaf(__shfl(v, k), denseW[k * 64 + c], acc);
            ftsd[(size_t)row * 64 + c] = elu(acc);
            return;
        }
        // ---------------- prep: weight transposes + pts SoA ----------------
        int i = (bid - 4) * 512 + t;      // 0 .. 32767
        if (i < 12288) {
            int k = i & 15, c = (i >> 4) % 3, o = i / 48;
            convT[(c * 16 + k) * 256 + o] = convW[i];
        }
        if (i < 4096) {
            int ii = i & 15, e = i >> 4;
            dw1T[ii * 256 + e] = dw1W[i];
            dw2T[ii * 256 + e] = dw2W[i];
        }
        if (i < 3072) {
            int k = i & 15, e = i >> 4;
            sdwT[k * 192 + e] = sdwW[i];
        }
        if (i < 24576) {
            int e2 = i % 192, o = i / 192;
            spwT[e2 * 128 + o] = spwW[i];
        }
        {
            int j = i & 8191, b2 = i >> 13;
#pragma unroll
            for (int d = 0; d < 3; ++d)
                ptsT[((size_t)b2 * 3 + d) * NN + j] = pts[((size_t)b2 * NN + j) * 3 + d];
        }
        return;
    }

    if (bid >= 4) {
        // =================== consumers: knn + xconv for 8 points ===========
        const int cb = bid - 4;
        const int wv = t >> 6, lane = t & 63;

        // ---- knn phase: wave wv -> global point gp = cb*8 + wv ----
        {
            const int gp = cb * 8 + wv;          // 0 .. 4*cons_cnt-1
            const int b = gp / cons_cnt;
            const int p = cons_p0 + (gp - b * cons_cnt);
            const int wid = b * PP + p;
            const float* pxT = ptsT + (size_t)b * 3 * NN;
            const float* pyT = pxT + NN;
            const float* pzT = pxT + 2 * NN;

            float rx = rep[(size_t)wid * 3 + 0];
            float ry = rep[(size_t)wid * 3 + 1];
            float rz = rep[(size_t)wid * 3 + 2];
            float a = __fadd_rn(__fadd_rn(__fmul_rn(rx, rx), __fmul_rn(ry, ry)), __fmul_rn(rz, rz));

            unsigned long long key[16];
#pragma unroll
            for (int s = 0; s < 16; ++s) key[s] = ~0ULL;

            unsigned tau = 0xFFFFFFFFu;
            int it = 0;
            for (int j = lane; j < NN; j += 64, ++it) {
                float qx = pxT[j], qy = pyT[j], qz = pzT[j];
                float cc = __fadd_rn(__fadd_rn(__fmul_rn(qx, qx), __fmul_rn(qy, qy)), __fmul_rn(qz, qz));
                float bs = __fadd_rn(__fadd_rn(__fmul_rn(rx, qx), __fmul_rn(ry, qy)), __fmul_rn(rz, qz));
                float d2 = __fadd_rn(__fsub_rn(a, __fmul_rn(2.0f, bs)), cc);
                unsigned fk = fkey(d2);
                if (fk <= tau) {
                    unsigned long long nk = ((unsigned long long)fk << 32) | (unsigned)j;
                    if (nk < key[15]) {
                        key[15] = nk;
#pragma unroll
                        for (int s2 = 15; s2 > 0; --s2) {
                            unsigned long long u = key[s2 - 1], w = key[s2];
                            bool sw = w < u;
                            key[s2 - 1] = sw ? w : u;
                            key[s2] = sw ? u : w;
                        }
                    }
                }
                if ((it & 7) == 7)
                    tau = wave_min_u32_dpp((unsigned)(key[15] >> 32));
            }

            int outv = 0;
#pragma unroll 1
            for (int r = 0; r < 16; ++r) {
                unsigned long long h = key[0];
#pragma unroll
                for (int off = 1; off < 64; off <<= 1) {
                    unsigned long long o = __shfl_xor(h, off);
                    h = (o < h) ? o : h;
                }
                if (lane == r) outv = (int)(unsigned)(h & 0xFFFFFFFFull);
                if (key[0] == h) {
#pragma unroll
                    for (int s2 = 0; s2 < 15; ++s2) key[s2] = key[s2 + 1];
                    key[15] = ~0ULL;
                }
            }
            if (lane < 16) sm.cons.kidx[wv][lane] = outv;
        }
        __syncthreads();

        // ---- xconv phase: 4 groups of 128 threads x 2 passes ----
        const int g = t >> 7, tl = t & 127, c64 = tl & 63;
#pragma unroll 1
        for (int pp = 0; pp < 2; ++pp) {
            const int pi = g * 2 + pp;
            const int gp2 = cb * 8 + pi;
            const int b = gp2 / cons_cnt;
            const int bp = b * PP + cons_p0 + (gp2 - b * cons_cnt);
            __syncthreads();

            if (tl < 16) {
                int id = sm.cons.kidx[pi][tl];
                sm.cons.nidx[g][tl] = id;
                const float* q = pts + ((size_t)b * NN + id) * 3;
                const float* rr = rep + (size_t)bp * 3;
                sm.cons.pl[g][tl][0] = q[0] - rr[0];
                sm.cons.pl[g][tl][1] = q[1] - rr[1];
                sm.cons.pl[g][tl][2] = q[2] - rr[2];
            }
            __syncthreads();

#pragma unroll
            for (int it = 0; it < 8; ++it) {
                int k = (tl >> 6) + it * 2;
                sm.cons.fcat[g][k][32 + c64] = ftsd[((size_t)b * NN + sm.cons.nidx[g][k]) * 64 + c64];
            }

#pragma unroll
            for (int r2 = 0; r2 < 4; ++r2) {
                int e = tl + 128 * r2; int k = e >> 5, j = e & 31;
                float acc = d1b[j];
                acc = fmaf(sm.cons.pl[g][k][0], d1W[j], acc);
                acc = fmaf(sm.cons.pl[g][k][1], d1W[32 + j], acc);
                acc = fmaf(sm.cons.pl[g][k][2], d1W[64 + j], acc);
                sm.cons.A1[g][k][j] = elu(acc);
            }
            __syncthreads();

#pragma unroll
            for (int r2 = 0; r2 < 4; ++r2) {
                int e = tl + 128 * r2; int k = e >> 5, j = e & 31;
                float acc = d2b[j];
#pragma unroll
                for (int c = 0; c < 32; ++c) acc = fmaf(sm.cons.A1[g][k][c], d2W[c * 32 + j], acc);
                sm.cons.fcat[g][k][j] = elu(acc);
            }
            __syncthreads();

            {
                float a0 = convb[tl], a1 = convb[tl + 128];
#pragma unroll
                for (int c = 0; c < 3; ++c)
#pragma unroll
                    for (int k = 0; k < 16; ++k) {
                        float p2 = sm.cons.pl[g][k][c];
                        const float* w = convT + (c * 16 + k) * 256 + tl;
                        a0 = fmaf(p2, w[0],   a0);
                        a1 = fmaf(p2, w[128], a1);
                    }
                sm.cons.Xm[g][tl >> 4][tl & 15] = elu(a0);
                sm.cons.Xm[g][(tl >> 4) + 8][tl & 15] = elu(a1);
            }
            __syncthreads();

            {
                int m = tl & 15, j0 = tl >> 4;
                float a0 = dw1b[tl], a1 = dw1b[tl + 128];
#pragma unroll
                for (int i = 0; i < 16; ++i) {
                    const float* w = dw1T + i * 256 + tl;
                    a0 = fmaf(sm.cons.Xm[g][i][j0],     w[0],   a0);
                    a1 = fmaf(sm.cons.Xm[g][i][j0 + 8], w[128], a1);
                }
                sm.cons.X2[g][j0][m] = elu(a0); sm.cons.X2[g][j0 + 8][m] = elu(a1);
            }
            __syncthreads();

            {
                int m = tl & 15, j0 = tl >> 4;
                float a0 = dw2b[tl], a1 = dw2b[tl + 128];
#pragma unroll
                for (int i = 0; i < 16; ++i) {
                    const float* w = dw2T + i * 256 + tl;
                    a0 = fmaf(sm.cons.X2[g][i][j0],     w[0],   a0);
                    a1 = fmaf(sm.cons.X2[g][i][j0 + 8], w[128], a1);
                }
                sm.cons.X3[g][j0][m] = a0; sm.cons.X3[g][j0 + 8][m] = a1;
            }
            __syncthreads();

#pragma unroll
            for (int r2 = 0; r2 < 12; ++r2) {
                int e = tl + 128 * r2; int a = e & 15, c = e >> 4;
                float acc = 0.0f;
#pragma unroll
                for (int q = 0; q < 16; ++q) acc = fmaf(sm.cons.X3[g][a][q], sm.cons.fcat[g][q][c], acc);
                sm.cons.fX[g][a][c] = acc;
            }
            __syncthreads();

#pragma unroll
            for (int r2 = 0; r2 < 2; ++r2) {
                int e = tl + 128 * r2;
                if (e < 192) {
                    int c = e >> 1;
                    float acc = sdwb[e];
#pragma unroll
                    for (int k = 0; k < 16; ++k) acc = fmaf(sm.cons.fX[g][k][c], sdwT[k * 192 + e], acc);
                    sm.cons.dsep[g][e] = acc;
                }
            }
            __syncthreads();

            {
                float a0 = spwb[tl];
#pragma unroll 16
                for (int e2 = 0; e2 < 192; ++e2)
                    a0 = fmaf(sm.cons.dsep[g][e2], spwT[e2 * 128 + tl], a0);
                outp[(size_t)bp * 128 + tl] = elu(a0);
            }
        }
        return;
    }

    // ============================== FPS ====================================
    __builtin_amdgcn_s_setprio(1);

    const int b = bid;
    const int lane = t & 63, wave = t >> 6;

    if (s0 == 1) {
        const float* pb = pts + (size_t)b * NN * 3;
        for (int i = t; i < NN; i += 512) {
            sm.fps.spx[i] = pb[3 * i + 0];
            sm.fps.spy[i] = pb[3 * i + 1];
            sm.fps.spz[i] = pb[3 * i + 2];
        }
    } else {
        // ptsT ready after chunk 0: coalesced SoA staging (identical values)
        const float* px_ = ptsT + (size_t)b * 3 * NN;
        for (int i = t; i < NN; i += 512) {
            sm.fps.spx[i] = px_[i];
            sm.fps.spy[i] = px_[NN + i];
            sm.fps.spz[i] = px_[2 * NN + i];
        }
    }
    __syncthreads();

    float px[16], py[16], pz[16], dist[16];
#pragma unroll
    for (int r = 0; r < 16; ++r) {
        px[r] = sm.fps.spx[t * 16 + r];
        py[r] = sm.fps.spy[t * 16 + r];
        pz[r] = sm.fps.spz[t * 16 + r];
    }

    float cx, cy, cz;
    if (s0 == 1) {
#pragma unroll
        for (int r = 0; r < 16; ++r) dist[r] = 1e10f;
        cx = sm.fps.spx[0]; cy = sm.fps.spy[0]; cz = sm.fps.spz[0];
        if (t == 0) {
            rep[(size_t)b * PP * 3 + 0] = cx;
            rep[(size_t)b * PP * 3 + 1] = cy;
            rep[(size_t)b * PP * 3 + 2] = cz;
        }
    } else {
#pragma unroll
        for (int r = 0; r < 16; ++r) dist[r] = fstate[((size_t)b * 16 + r) * 512 + t];
        const float* rp = rep + ((size_t)b * PP + s0 - 1) * 3;
        cx = rp[0]; cy = rp[1]; cz = rp[2];
    }

    int buf = 0;
    for (int s = s0; s < s1; ++s) {
        float bv = -1.0f; int bi = 0;
#pragma unroll
        for (int r = 0; r < 16; ++r) {
            float dx = __fsub_rn(px[r], cx);
            float dy = __fsub_rn(py[r], cy);
            float dz = __fsub_rn(pz[r], cz);
            float d = __fadd_rn(__fadd_rn(__fmul_rn(dx, dx), __fmul_rn(dy, dy)), __fmul_rn(dz, dz));
            float nd = fminf(dist[r], d);
            dist[r] = nd;
            bool tk = nd > bv;
            bi = tk ? (t * 16 + r) : bi;
            bv = fmaxf(nd, bv);
        }

        float wmax = wave_max_dpp(bv);
        unsigned long long mask = __ballot(bv == wmax);
        int wl = __ffsll(mask) - 1;
        int wbi = __shfl(bi, wl);

        if (lane == 0)
            sm.fps.partk[buf][wave] = ((unsigned long long)__float_as_uint(wmax) << 32)
                                    | (unsigned)(8191 - wbi);
        __syncthreads();

        unsigned long long kk = sm.fps.partk[buf][0];
#pragma unroll
        for (int q = 1; q < 8; ++q) {
            unsigned long long c = sm.fps.partk[buf][q];
            kk = c > kk ? c : kk;
        }
        int widx = 8191 - (int)(unsigned)(kk & 0xFFFFFFFFULL);
        cx = sm.fps.spx[widx]; cy = sm.fps.spy[widx]; cz = sm.fps.spz[widx];
        if (t == 0) {
            float* rp = rep + ((size_t)b * PP + s) * 3;
            rp[0] = cx; rp[1] = cy; rp[2] = cz;
        }
        buf ^= 1;
    }

    if (s1 < PP) {
#pragma unroll
        for (int r = 0; r < 16; ++r) fstate[((size_t)b * 16 + r) * 512 + t] = dist[r];
    }
}

// ---------------------------------------------------------------------------
// Tail KNN for p in [p_base, p_base+cnt) per batch (full occupancy).
// ---------------------------------------------------------------------------
__global__ __launch_bounds__(256) void knn_kernel(const float* __restrict__ ptsT,
                                                  const float* __restrict__ rep,
                                                  int* __restrict__ kidx,
                                                  int p_base, int cnt) {
    const int wl_ = blockIdx.x * 4 + (threadIdx.x >> 6);   // 0 .. 4*cnt-1
    const int lane = threadIdx.x & 63;
    const int b = wl_ / cnt;
    const int wid = b * PP + p_base + (wl_ - b * cnt);
    const float* pxT = ptsT + (size_t)b * 3 * NN;
    const float* pyT = pxT + NN;
    const float* pzT = pxT + 2 * NN;

    float rx = rep[(size_t)wid * 3 + 0];
    float ry = rep[(size_t)wid * 3 + 1];
    float rz = rep[(size_t)wid * 3 + 2];
    float a = __fadd_rn(__fadd_rn(__fmul_rn(rx, rx), __fmul_rn(ry, ry)), __fmul_rn(rz, rz));

    unsigned long long key[16];
#pragma unroll
    for (int s = 0; s < 16; ++s) key[s] = ~0ULL;

    unsigned tau = 0xFFFFFFFFu;
    int it = 0;
    for (int j = lane; j < NN; j += 64, ++it) {
        float qx = pxT[j], qy = pyT[j], qz = pzT[j];
        float cc = __fadd_rn(__fadd_rn(__fmul_rn(qx, qx), __fmul_rn(qy, qy)), __fmul_rn(qz, qz));
        float bs = __fadd_rn(__fadd_rn(__fmul_rn(rx, qx), __fmul_rn(ry, qy)), __fmul_rn(rz, qz));
        float d2 = __fadd_rn(__fsub_rn(a, __fmul_rn(2.0f, bs)), cc);
        unsigned fk = fkey(d2);
        if (fk <= tau) {
            unsigned long long nk = ((unsigned long long)fk << 32) | (unsigned)j;
            if (nk < key[15]) {
                key[15] = nk;
#pragma unroll
                for (int s2 = 15; s2 > 0; --s2) {
                    unsigned long long u = key[s2 - 1], w = key[s2];
                    bool sw = w < u;
                    key[s2 - 1] = sw ? w : u;
                    key[s2] = sw ? u : w;
                }
            }
        }
        if ((it & 7) == 7)
            tau = wave_min_u32_dpp((unsigned)(key[15] >> 32));
    }

    int outv = 0;
#pragma unroll 1
    for (int r = 0; r < 16; ++r) {
        unsigned long long h = key[0];
#pragma unroll
        for (int off = 1; off < 64; off <<= 1) {
            unsigned long long o = __shfl_xor(h, off);
            h = (o < h) ? o : h;
        }
        if (lane == r) outv = (int)(unsigned)(h & 0xFFFFFFFFull);
        if (key[0] == h) {
#pragma unroll
            for (int s2 = 0; s2 < 15; ++s2) key[s2] = key[s2 + 1];
            key[15] = ~0ULL;
        }
    }
    if (lane < 16) kidx[(size_t)wid * 16 + lane] = outv;
}

// ---------------------------------------------------------------------------
// Tail XConv for p in [p_base, p_base+cnt) per batch.
// ---------------------------------------------------------------------------
__global__ __launch_bounds__(128) void xconv_kernel(
    const float* __restrict__ pts, const float* __restrict__ rep,
    const float* __restrict__ ftsd, const int* __restrict__ kidx,
    const float* __restrict__ d1W, const float* __restrict__ d1b,
    const float* __restrict__ d2W, const float* __restrict__ d2b,
    const float* __restrict__ convT, const float* __restrict__ convb,
    const float* __restrict__ dw1T, const float* __restrict__ dw1b,
    const float* __restrict__ dw2T, const float* __restrict__ dw2b,
    const float* __restrict__ sdwT, const float* __restrict__ sdwb,
    const float* __restrict__ spwT, const float* __restrict__ spwb,
    float* __restrict__ outp, int p_base, int cnt) {
    const int bl = blockIdx.x;            // 0 .. 4*cnt-1
    const int b = bl / cnt;
    const int bp = b * PP + p_base + (bl - b * cnt);
    const int t = threadIdx.x;
    const int c64 = t & 63;

    __shared__ float pl[16][3];
    __shared__ int nidx[16];
    __shared__ float fcat[16][96];
    __shared__ float A1[16][32];
    __shared__ float Xm[16][17];
    __shared__ float X2[16][17];
    __shared__ float X3[16][17];
    __shared__ float fX[16][97];
    __shared__ float dsep[192];

    if (t < 16) {
        int id = kidx[(size_t)bp * 16 + t];
        nidx[t] = id;
        const float* q = pts + ((size_t)b * NN + id) * 3;
        const float* rr = rep + (size_t)bp * 3;
        pl[t][0] = q[0] - rr[0];
        pl[t][1] = q[1] - rr[1];
        pl[t][2] = q[2] - rr[2];
    }
    __syncthreads();

#pragma unroll
    for (int it = 0; it < 8; ++it) {
        int k = (t >> 6) + it * 2;
        fcat[k][32 + c64] = ftsd[((size_t)b * NN + nidx[k]) * 64 + c64];
    }

#pragma unroll
    for (int r2 = 0; r2 < 4; ++r2) {
        int e = t + 128 * r2; int k = e >> 5, j = e & 31;
        float acc = d1b[j];
        acc = fmaf(pl[k][0], d1W[j], acc);
        acc = fmaf(pl[k][1], d1W[32 + j], acc);
        acc = fmaf(pl[k][2], d1W[64 + j], acc);
        A1[k][j] = elu(acc);
    }
    __syncthreads();

#pragma unroll
    for (int r2 = 0; r2 < 4; ++r2) {
        int e = t + 128 * r2; int k = e >> 5, j = e & 31;
        float acc = d2b[j];
#pragma unroll
        for (int c = 0; c < 32; ++c) acc = fmaf(A1[k][c], d2W[c * 32 + j], acc);
        fcat[k][j] = elu(acc);
    }
    __syncthreads();

    {
        float a0 = convb[t], a1 = convb[t + 128];
#pragma unroll
        for (int c = 0; c < 3; ++c)
#pragma unroll
            for (int k = 0; k < 16; ++k) {
                float p = pl[k][c];
                const float* w = convT + (c * 16 + k) * 256 + t;
                a0 = fmaf(p, w[0],   a0);
                a1 = fmaf(p, w[128], a1);
            }
        Xm[t >> 4][t & 15] = elu(a0);
        Xm[(t >> 4) + 8][t & 15] = elu(a1);
    }
    __syncthreads();

    {
        int m = t & 15, j0 = t >> 4;
        float a0 = dw1b[t], a1 = dw1b[t + 128];
#pragma unroll
        for (int i = 0; i < 16; ++i) {
            const float* w = dw1T + i * 256 + t;
            a0 = fmaf(Xm[i][j0],     w[0],   a0);
            a1 = fmaf(Xm[i][j0 + 8], w[128], a1);
        }
        X2[j0][m] = elu(a0); X2[j0 + 8][m] = elu(a1);
    }
    __syncthreads();

    {
        int m = t & 15, j0 = t >> 4;
        float a0 = dw2b[t], a1 = dw2b[t + 128];
#pragma unroll
        for (int i = 0; i < 16; ++i) {
            const float* w = dw2T + i * 256 + t;
            a0 = fmaf(X2[i][j0],     w[0],   a0);
            a1 = fmaf(X2[i][j0 + 8], w[128], a1);
        }
        X3[j0][m] = a0; X3[j0 + 8][m] = a1;
    }
    __syncthreads();

#pragma unroll
    for (int r2 = 0; r2 < 12; ++r2) {
        int e = t + 128 * r2; int a = e & 15, c = e >> 4;
        float acc = 0.0f;
#pragma unroll
        for (int q = 0; q < 16; ++q) acc = fmaf(X3[a][q], fcat[q][c], acc);
        fX[a][c] = acc;
    }
    __syncthreads();

#pragma unroll
    for (int r2 = 0; r2 < 2; ++r2) {
        int e = t + 128 * r2;
        if (e < 192) {
            int c = e >> 1;
            float acc = sdwb[e];
#pragma unroll
            for (int k = 0; k < 16; ++k) acc = fmaf(fX[k][c], sdwT[k * 192 + e], acc);
            dsep[e] = acc;
        }
    }
    __syncthreads();

    {
        float a0 = spwb[t];
#pragma unroll 16
        for (int e2 = 0; e2 < 192; ++e2)
            a0 = fmaf(dsep[e2], spwT[e2 * 128 + t], a0);
        outp[(size_t)bp * 128 + t] = elu(a0);
    }
}

extern "C" void kernel_launch(void* const* d_in, const int* in_sizes, int n_in,
                              void* d_out, int out_size, void* d_ws, size_t ws_size,
                              hipStream_t stream) {
    const float* pts    = (const float*)d_in[0];
    const float* fts    = (const float*)d_in[1];
    const float* denseW = (const float*)d_in[2];
    const float* denseb = (const float*)d_in[3];
    const float* d1W    = (const float*)d_in[4];
    const float* d1b    = (const float*)d_in[5];
    const float* d2W    = (const float*)d_in[6];
    const float* d2b    = (const float*)d_in[7];
    const float* convW  = (const float*)d_in[8];
    const float* convb  = (const float*)d_in[9];
    const float* dw1W   = (const float*)d_in[10];
    const float* dw1b   = (const float*)d_in[11];
    const float* dw2W   = (const float*)d_in[12];
    const float* dw2b   = (const float*)d_in[13];
    const float* sdwW   = (const float*)d_in[14];
    const float* sdwb   = (const float*)d_in[15];
    const float* spwW   = (const float*)d_in[16];
    const float* spwb   = (const float*)d_in[17];

    float* rep  = (float*)d_out;                       // [B,P,3]
    float* outp = (float*)d_out + (size_t)BB * PP * 3; // [B,P,128]

    float* ftsd = (float*)d_ws;                                                // 8 MB
    int*   kidx = (int*)((char*)d_ws + (size_t)BB * NN * CIN * sizeof(float)); // 512 KB
    float* wts  = (float*)((char*)d_ws + (size_t)BB * NN * CIN * sizeof(float)
                                       + (size_t)BB * PP * KNB * sizeof(int));
    float* convT  = wts;              // 12288
    float* dw1T   = wts + 12288;      // 4096
    float* dw2T   = wts + 16384;      // 4096
    float* sdwT   = wts + 20480;      // 3072
    float* spwT   = wts + 23552;      // 24576
    float* ptsT   = wts + 48128;      // 98304 (B*3*N SoA)
    float* fstate = wts + 146432;     // 32768 (B*16*512 dist state)

    // chunk 0: FPS rounds [1,CH0) + prep + dense
    mega_kernel<<<DENSE_BASE + BB * NN / 8, 512, 0, stream>>>(
        pts, rep, fts, denseW, denseb, ftsd, convW, dw1W, dw2W, sdwW, spwW,
        convT, dw1T, dw2T, sdwT, spwT, ptsT, fstate,
        d1W, d1b, d2W, d2b, convb, dw1b, dw2b, sdwb, spwb, outp,
        1, CH0, 0, 0, 0);
    // chunk 1: FPS rounds [CH0,2048) + consumers for points [0,CH0)/batch
    mega_kernel<<<4 + (BB * CH0) / 8, 512, 0, stream>>>(
        pts, rep, fts, denseW, denseb, ftsd, convW, dw1W, dw2W, sdwW, spwW,
        convT, dw1T, dw2T, sdwT, spwT, ptsT, fstate,
        d1W, d1b, d2W, d2b, convb, dw1b, dw2b, sdwb, spwb, outp,
        CH0, PP, 1, 0, CH0);
    // tail: points [CH0,2048)/batch at full occupancy
    knn_kernel<<<BB * R1 / 4, 256, 0, stream>>>(ptsT, rep, kidx, CH0, R1);
    xconv_kernel<<<BB * R1, 128, 0, stream>>>(pts, rep, ftsd, kidx,
                                              d1W, d1b, d2W, d2b, convT, convb,
                                              dw1T, dw1b, dw2T, dw2b,
                                              sdwT, sdwb, spwT, spwb, outp, CH0, R1);
}

// Round 17
// 2197.221 us; speedup vs baseline: 1.3859x; 1.3859x over previous
//
#include <hip/hip_runtime.h>

#define BB 4
#define NN 8192
#define PP 2048
#define KNB 16
#define CIN 64
#define COUT 128
#define CHUNK 1024

__device__ __forceinline__ float elu(float x) { return x > 0.0f ? x : expm1f(x); }

__device__ __forceinline__ unsigned fkey(float d) {
    unsigned u = __float_as_uint(d);
    unsigned m = (unsigned)((int)u >> 31);
    return u ^ (m | 0x80000000u);
}

// 64-lane max reduce on the VALU pipe via DPP. (HW-verified rounds 9-15)
__device__ __forceinline__ float wave_max_dpp(float v) {
#define DPP_STEP(ctrl)                                                         \
    {                                                                          \
        int x = __float_as_int(v);                                             \
        int y = __builtin_amdgcn_update_dpp(x, x, (ctrl), 0xf, 0xf, false);    \
        v = fmaxf(v, __int_as_float(y));                                       \
    }
    DPP_STEP(0x111) DPP_STEP(0x112) DPP_STEP(0x114)
    DPP_STEP(0x118) DPP_STEP(0x142) DPP_STEP(0x143)
#undef DPP_STEP
    return __int_as_float(__builtin_amdgcn_readlane(__float_as_int(v), 63));
}

__device__ __forceinline__ unsigned wave_min_u32_dpp(unsigned v) {
#define DPP_STEP(ctrl)                                                         \
    {                                                                          \
        int y = __builtin_amdgcn_update_dpp((int)v, (int)v, (ctrl), 0xf, 0xf, false); \
        v = min(v, (unsigned)y);                                               \
    }
    DPP_STEP(0x111) DPP_STEP(0x112) DPP_STEP(0x114)
    DPP_STEP(0x118) DPP_STEP(0x142) DPP_STEP(0x143)
#undef DPP_STEP
    return (unsigned)__builtin_amdgcn_readlane((int)v, 63);
}

struct FpsSmem {
    float spx[NN], spy[NN], spz[NN];
    unsigned long long partk[2][8];
};
struct ConsSmem {
    int kidx[8][16];
    float pl[4][16][3];
    int nidx[4][16];
    float fcat[4][16][96];
    float A1[4][16][32];
    float Xm[4][16][17];
    float X2[4][16][17];
    float X3[4][16][17];
    float fX[4][16][97];
    float dsep[4][192];
};
union Smem { FpsSmem fps; ConsSmem cons; };

#define PREP_BLOCKS 64
#define DENSE_BASE (4 + PREP_BLOCKS)

// ---------------------------------------------------------------------------
// Mega kernel. blocks 0..3: FPS rounds [s0,s1) (state save/restore in ws).
// mode 0 (chunk 0): blocks 4..67 prep, 68..4163 dense.
// mode 1 (chunk 1): blocks 4..515 = fused knn+xconv consumers for the 1024
//   points/batch finalized by the PREVIOUS launch (stream-ordered).
// Consumer math identical to standalone kernels -> bitwise-identical output.
// ---------------------------------------------------------------------------
__global__ __launch_bounds__(512) void mega_kernel(
    const float* __restrict__ pts, float* __restrict__ rep,
    const float* __restrict__ fts, const float* __restrict__ denseW,
    const float* __restrict__ denseb, float* __restrict__ ftsd,
    const float* __restrict__ convW, const float* __restrict__ dw1W,
    const float* __restrict__ dw2W, const float* __restrict__ sdwW,
    const float* __restrict__ spwW,
    float* __restrict__ convT, float* __restrict__ dw1T, float* __restrict__ dw2T,
    float* __restrict__ sdwT, float* __restrict__ spwT, float* __restrict__ ptsT,
    float* __restrict__ fstate,
    const float* __restrict__ d1W, const float* __restrict__ d1b,
    const float* __restrict__ d2W, const float* __restrict__ d2b,
    const float* __restrict__ convb, const float* __restrict__ dw1b,
    const float* __restrict__ dw2b, const float* __restrict__ sdwb,
    const float* __restrict__ spwb, float* __restrict__ outp,
    int s0, int s1, int mode, int cons_p0) {
    const int bid = blockIdx.x;
    const int t = threadIdx.x;

    __shared__ Smem sm;

    if (bid >= 4 && mode == 0) {
        if (bid >= DENSE_BASE) {
            // ---------------- dense: 8 rows/block, one wave per row --------
            const int row = (bid - DENSE_BASE) * 8 + (t >> 6);
            const int c = t & 63;
            float v = fts[(size_t)row * 64 + c];
            float acc = denseb[c];
#pragma unroll 8
            for (int k = 0; k < 64; ++k) acc = fmaf(__shfl(v, k), denseW[k * 64 + c], acc);
            ftsd[(size_t)row * 64 + c] = elu(acc);
            return;
        }
        // ---------------- prep: weight transposes + pts SoA ----------------
        int i = (bid - 4) * 512 + t;      // 0 .. 32767
        if (i < 12288) {
            int k = i & 15, c = (i >> 4) % 3, o = i / 48;
            convT[(c * 16 + k) * 256 + o] = convW[i];
        }
        if (i < 4096) {
            int ii = i & 15, e = i >> 4;
            dw1T[ii * 256 + e] = dw1W[i];
            dw2T[ii * 256 + e] = dw2W[i];
        }
        if (i < 3072) {
            int k = i & 15, e = i >> 4;
            sdwT[k * 192 + e] = sdwW[i];
        }
        if (i < 24576) {
            int e2 = i % 192, o = i / 192;
            spwT[e2 * 128 + o] = spwW[i];
        }
        {
            int j = i & 8191, b2 = i >> 13;
#pragma unroll
            for (int d = 0; d < 3; ++d)
                ptsT[((size_t)b2 * 3 + d) * NN + j] = pts[((size_t)b2 * NN + j) * 3 + d];
        }
        return;
    }

    if (bid >= 4) {
        // =================== consumers: knn + xconv for 8 points ===========
        const int cb = bid - 4;           // 0..511
        const int wv = t >> 6, lane = t & 63;

        // ---- knn phase: wave wv -> global point gp = cb*8 + wv ----
        {
            const int gp = cb * 8 + wv;          // 0..4095
            const int b = gp >> 10;              // 1024 pts per batch
            const int p = cons_p0 + (gp & 1023);
            const int wid = b * PP + p;
            const float* pxT = ptsT + (size_t)b * 3 * NN;
            const float* pyT = pxT + NN;
            const float* pzT = pxT + 2 * NN;

            float rx = rep[(size_t)wid * 3 + 0];
            float ry = rep[(size_t)wid * 3 + 1];
            float rz = rep[(size_t)wid * 3 + 2];
            float a = __fadd_rn(__fadd_rn(__fmul_rn(rx, rx), __fmul_rn(ry, ry)), __fmul_rn(rz, rz));

            unsigned long long key[16];
#pragma unroll
            for (int s = 0; s < 16; ++s) key[s] = ~0ULL;

            unsigned tau = 0xFFFFFFFFu;
            int it = 0;
            for (int j = lane; j < NN; j += 64, ++it) {
                float qx = pxT[j], qy = pyT[j], qz = pzT[j];
                float cc = __fadd_rn(__fadd_rn(__fmul_rn(qx, qx), __fmul_rn(qy, qy)), __fmul_rn(qz, qz));
                float bs = __fadd_rn(__fadd_rn(__fmul_rn(rx, qx), __fmul_rn(ry, qy)), __fmul_rn(rz, qz));
                float d2 = __fadd_rn(__fsub_rn(a, __fmul_rn(2.0f, bs)), cc);
                unsigned fk = fkey(d2);
                if (fk <= tau) {
                    unsigned long long nk = ((unsigned long long)fk << 32) | (unsigned)j;
                    if (nk < key[15]) {
                        key[15] = nk;
#pragma unroll
                        for (int s2 = 15; s2 > 0; --s2) {
                            unsigned long long u = key[s2 - 1], w = key[s2];
                            bool sw = w < u;
                            key[s2 - 1] = sw ? w : u;
                            key[s2] = sw ? u : w;
                        }
                    }
                }
                if ((it & 7) == 7)
                    tau = wave_min_u32_dpp((unsigned)(key[15] >> 32));
            }

            int outv = 0;
#pragma unroll 1
            for (int r = 0; r < 16; ++r) {
                unsigned long long h = key[0];
#pragma unroll
                for (int off = 1; off < 64; off <<= 1) {
                    unsigned long long o = __shfl_xor(h, off);
                    h = (o < h) ? o : h;
                }
                if (lane == r) outv = (int)(unsigned)(h & 0xFFFFFFFFull);
                if (key[0] == h) {
#pragma unroll
                    for (int s2 = 0; s2 < 15; ++s2) key[s2] = key[s2 + 1];
                    key[15] = ~0ULL;
                }
            }
            if (lane < 16) sm.cons.kidx[wv][lane] = outv;
        }
        __syncthreads();

        // ---- xconv phase: 4 groups of 128 threads x 2 passes ----
        const int g = t >> 7, tl = t & 127, c64 = tl & 63;
#pragma unroll 1
        for (int pp = 0; pp < 2; ++pp) {
            const int pi = g * 2 + pp;
            const int gp2 = cb * 8 + pi;
            const int b = gp2 >> 10;
            const int bp = b * PP + cons_p0 + (gp2 & 1023);
            __syncthreads();

            if (tl < 16) {
                int id = sm.cons.kidx[pi][tl];
                sm.cons.nidx[g][tl] = id;
                const float* q = pts + ((size_t)b * NN + id) * 3;
                const float* rr = rep + (size_t)bp * 3;
                sm.cons.pl[g][tl][0] = q[0] - rr[0];
                sm.cons.pl[g][tl][1] = q[1] - rr[1];
                sm.cons.pl[g][tl][2] = q[2] - rr[2];
            }
            __syncthreads();

#pragma unroll
            for (int it = 0; it < 8; ++it) {
                int k = (tl >> 6) + it * 2;
                sm.cons.fcat[g][k][32 + c64] = ftsd[((size_t)b * NN + sm.cons.nidx[g][k]) * 64 + c64];
            }

#pragma unroll
            for (int r2 = 0; r2 < 4; ++r2) {
                int e = tl + 128 * r2; int k = e >> 5, j = e & 31;
                float acc = d1b[j];
                acc = fmaf(sm.cons.pl[g][k][0], d1W[j], acc);
                acc = fmaf(sm.cons.pl[g][k][1], d1W[32 + j], acc);
                acc = fmaf(sm.cons.pl[g][k][2], d1W[64 + j], acc);
                sm.cons.A1[g][k][j] = elu(acc);
            }
            __syncthreads();

#pragma unroll
            for (int r2 = 0; r2 < 4; ++r2) {
                int e = tl + 128 * r2; int k = e >> 5, j = e & 31;
                float acc = d2b[j];
#pragma unroll
                for (int c = 0; c < 32; ++c) acc = fmaf(sm.cons.A1[g][k][c], d2W[c * 32 + j], acc);
                sm.cons.fcat[g][k][j] = elu(acc);
            }
            __syncthreads();

            {
                float a0 = convb[tl], a1 = convb[tl + 128];
#pragma unroll
                for (int c = 0; c < 3; ++c)
#pragma unroll
                    for (int k = 0; k < 16; ++k) {
                        float p2 = sm.cons.pl[g][k][c];
                        const float* w = convT + (c * 16 + k) * 256 + tl;
                        a0 = fmaf(p2, w[0],   a0);
                        a1 = fmaf(p2, w[128], a1);
                    }
                sm.cons.Xm[g][tl >> 4][tl & 15] = elu(a0);
                sm.cons.Xm[g][(tl >> 4) + 8][tl & 15] = elu(a1);
            }
            __syncthreads();

            {
                int m = tl & 15, j0 = tl >> 4;
                float a0 = dw1b[tl], a1 = dw1b[tl + 128];
#pragma unroll
                for (int i = 0; i < 16; ++i) {
                    const float* w = dw1T + i * 256 + tl;
                    a0 = fmaf(sm.cons.Xm[g][i][j0],     w[0],   a0);
                    a1 = fmaf(sm.cons.Xm[g][i][j0 + 8], w[128], a1);
                }
                sm.cons.X2[g][j0][m] = elu(a0); sm.cons.X2[g][j0 + 8][m] = elu(a1);
            }
            __syncthreads();

            {
                int m = tl & 15, j0 = tl >> 4;
                float a0 = dw2b[tl], a1 = dw2b[tl + 128];
#pragma unroll
                for (int i = 0; i < 16; ++i) {
                    const float* w = dw2T + i * 256 + tl;
                    a0 = fmaf(sm.cons.X2[g][i][j0],     w[0],   a0);
                    a1 = fmaf(sm.cons.X2[g][i][j0 + 8], w[128], a1);
                }
                sm.cons.X3[g][j0][m] = a0; sm.cons.X3[g][j0 + 8][m] = a1;
            }
            __syncthreads();

#pragma unroll
            for (int r2 = 0; r2 < 12; ++r2) {
                int e = tl + 128 * r2; int a = e & 15, c = e >> 4;
                float acc = 0.0f;
#pragma unroll
                for (int q = 0; q < 16; ++q) acc = fmaf(sm.cons.X3[g][a][q], sm.cons.fcat[g][q][c], acc);
                sm.cons.fX[g][a][c] = acc;
            }
            __syncthreads();

#pragma unroll
            for (int r2 = 0; r2 < 2; ++r2) {
                int e = tl + 128 * r2;
                if (e < 192) {
                    int c = e >> 1;
                    float acc = sdwb[e];
#pragma unroll
                    for (int k = 0; k < 16; ++k) acc = fmaf(sm.cons.fX[g][k][c], sdwT[k * 192 + e], acc);
                    sm.cons.dsep[g][e] = acc;
                }
            }
            __syncthreads();

            {
                float a0 = spwb[tl];
#pragma unroll 16
                for (int e2 = 0; e2 < 192; ++e2)
                    a0 = fmaf(sm.cons.dsep[g][e2], spwT[e2 * 128 + tl], a0);
                outp[(size_t)bp * 128 + tl] = elu(a0);
            }
        }
        return;
    }

    // ============================== FPS ====================================
    __builtin_amdgcn_s_setprio(1);

    const int b = bid;
    const int lane = t & 63, wave = t >> 6;

    if (s0 == 1) {
        const float* pb = pts + (size_t)b * NN * 3;
        for (int i = t; i < NN; i += 512) {
            sm.fps.spx[i] = pb[3 * i + 0];
            sm.fps.spy[i] = pb[3 * i + 1];
            sm.fps.spz[i] = pb[3 * i + 2];
        }
    } else {
        // ptsT ready after chunk 0: coalesced SoA staging (identical values)
        const float* px_ = ptsT + (size_t)b * 3 * NN;
        for (int i = t; i < NN; i += 512) {
            sm.fps.spx[i] = px_[i];
            sm.fps.spy[i] = px_[NN + i];
            sm.fps.spz[i] = px_[2 * NN + i];
        }
    }
    __syncthreads();

    float px[16], py[16], pz[16], dist[16];
#pragma unroll
    for (int r = 0; r < 16; ++r) {
        px[r] = sm.fps.spx[t * 16 + r];
        py[r] = sm.fps.spy[t * 16 + r];
        pz[r] = sm.fps.spz[t * 16 + r];
    }

    float cx, cy, cz;
    if (s0 == 1) {
#pragma unroll
        for (int r = 0; r < 16; ++r) dist[r] = 1e10f;
        cx = sm.fps.spx[0]; cy = sm.fps.spy[0]; cz = sm.fps.spz[0];
        if (t == 0) {
            rep[(size_t)b * PP * 3 + 0] = cx;
            rep[(size_t)b * PP * 3 + 1] = cy;
            rep[(size_t)b * PP * 3 + 2] = cz;
        }
    } else {
#pragma unroll
        for (int r = 0; r < 16; ++r) dist[r] = fstate[((size_t)b * 16 + r) * 512 + t];
        const float* rp = rep + ((size_t)b * PP + s0 - 1) * 3;
        cx = rp[0]; cy = rp[1]; cz = rp[2];
    }

    int buf = 0;
    for (int s = s0; s < s1; ++s) {
        float bv = -1.0f; int bi = 0;
#pragma unroll
        for (int r = 0; r < 16; ++r) {
            float dx = __fsub_rn(px[r], cx);
            float dy = __fsub_rn(py[r], cy);
            float dz = __fsub_rn(pz[r], cz);
            float d = __fadd_rn(__fadd_rn(__fmul_rn(dx, dx), __fmul_rn(dy, dy)), __fmul_rn(dz, dz));
            float nd = fminf(dist[r], d);
            dist[r] = nd;
            bool tk = nd > bv;
            bi = tk ? (t * 16 + r) : bi;
            bv = fmaxf(nd, bv);
        }

        float wmax = wave_max_dpp(bv);
        unsigned long long mask = __ballot(bv == wmax);
        int wl = __ffsll(mask) - 1;
        int wbi = __shfl(bi, wl);

        if (lane == 0)
            sm.fps.partk[buf][wave] = ((unsigned long long)__float_as_uint(wmax) << 32)
                                    | (unsigned)(8191 - wbi);
        __syncthreads();

        unsigned long long kk = sm.fps.partk[buf][0];
#pragma unroll
        for (int q = 1; q < 8; ++q) {
            unsigned long long c = sm.fps.partk[buf][q];
            kk = c > kk ? c : kk;
        }
        int widx = 8191 - (int)(unsigned)(kk & 0xFFFFFFFFULL);
        cx = sm.fps.spx[widx]; cy = sm.fps.spy[widx]; cz = sm.fps.spz[widx];
        if (t == 0) {
            float* rp = rep + ((size_t)b * PP + s) * 3;
            rp[0] = cx; rp[1] = cy; rp[2] = cz;
        }
        buf ^= 1;
    }

    if (s1 < PP) {
#pragma unroll
        for (int r = 0; r < 16; ++r) fstate[((size_t)b * 16 + r) * 512 + t] = dist[r];
    }
}

// ---------------------------------------------------------------------------
// Tail KNN for p in [p_base, p_base+1024) per batch (full occupancy).
// ---------------------------------------------------------------------------
__global__ __launch_bounds__(256) void knn_kernel(const float* __restrict__ ptsT,
                                                  const float* __restrict__ rep,
                                                  int* __restrict__ kidx, int p_base) {
    const int wl_ = blockIdx.x * 4 + (threadIdx.x >> 6);   // 0..4095
    const int lane = threadIdx.x & 63;
    const int b = wl_ >> 10;
    const int wid = b * PP + p_base + (wl_ & 1023);
    const float* pxT = ptsT + (size_t)b * 3 * NN;
    const float* pyT = pxT + NN;
    const float* pzT = pxT + 2 * NN;

    float rx = rep[(size_t)wid * 3 + 0];
    float ry = rep[(size_t)wid * 3 + 1];
    float rz = rep[(size_t)wid * 3 + 2];
    float a = __fadd_rn(__fadd_rn(__fmul_rn(rx, rx), __fmul_rn(ry, ry)), __fmul_rn(rz, rz));

    unsigned long long key[16];
#pragma unroll
    for (int s = 0; s < 16; ++s) key[s] = ~0ULL;

    unsigned tau = 0xFFFFFFFFu;
    int it = 0;
    for (int j = lane; j < NN; j += 64, ++it) {
        float qx = pxT[j], qy = pyT[j], qz = pzT[j];
        float cc = __fadd_rn(__fadd_rn(__fmul_rn(qx, qx), __fmul_rn(qy, qy)), __fmul_rn(qz, qz));
        float bs = __fadd_rn(__fadd_rn(__fmul_rn(rx, qx), __fmul_rn(ry, qy)), __fmul_rn(rz, qz));
        float d2 = __fadd_rn(__fsub_rn(a, __fmul_rn(2.0f, bs)), cc);
        unsigned fk = fkey(d2);
        if (fk <= tau) {
            unsigned long long nk = ((unsigned long long)fk << 32) | (unsigned)j;
            if (nk < key[15]) {
                key[15] = nk;
#pragma unroll
                for (int s2 = 15; s2 > 0; --s2) {
                    unsigned long long u = key[s2 - 1], w = key[s2];
                    bool sw = w < u;
                    key[s2 - 1] = sw ? w : u;
                    key[s2] = sw ? u : w;
                }
            }
        }
        if ((it & 7) == 7)
            tau = wave_min_u32_dpp((unsigned)(key[15] >> 32));
    }

    int outv = 0;
#pragma unroll 1
    for (int r = 0; r < 16; ++r) {
        unsigned long long h = key[0];
#pragma unroll
        for (int off = 1; off < 64; off <<= 1) {
            unsigned long long o = __shfl_xor(h, off);
            h = (o < h) ? o : h;
        }
        if (lane == r) outv = (int)(unsigned)(h & 0xFFFFFFFFull);
        if (key[0] == h) {
#pragma unroll
            for (int s2 = 0; s2 < 15; ++s2) key[s2] = key[s2 + 1];
            key[15] = ~0ULL;
        }
    }
    if (lane < 16) kidx[(size_t)wid * 16 + lane] = outv;
}

// ---------------------------------------------------------------------------
// Tail XConv for p in [p_base, p_base+1024) per batch.
// ---------------------------------------------------------------------------
__global__ __launch_bounds__(128) void xconv_kernel(
    const float* __restrict__ pts, const float* __restrict__ rep,
    const float* __restrict__ ftsd, const int* __restrict__ kidx,
    const float* __restrict__ d1W, const float* __restrict__ d1b,
    const float* __restrict__ d2W, const float* __restrict__ d2b,
    const float* __restrict__ convT, const float* __restrict__ convb,
    const float* __restrict__ dw1T, const float* __restrict__ dw1b,
    const float* __restrict__ dw2T, const float* __restrict__ dw2b,
    const float* __restrict__ sdwT, const float* __restrict__ sdwb,
    const float* __restrict__ spwT, const float* __restrict__ spwb,
    float* __restrict__ outp, int p_base) {
    const int bl = blockIdx.x;            // 0..4095
    const int b = bl >> 10;
    const int bp = b * PP + p_base + (bl & 1023);
    const int t = threadIdx.x;
    const int c64 = t & 63;

    __shared__ float pl[16][3];
    __shared__ int nidx[16];
    __shared__ float fcat[16][96];
    __shared__ float A1[16][32];
    __shared__ float Xm[16][17];
    __shared__ float X2[16][17];
    __shared__ float X3[16][17];
    __shared__ float fX[16][97];
    __shared__ float dsep[192];

    if (t < 16) {
        int id = kidx[(size_t)bp * 16 + t];
        nidx[t] = id;
        const float* q = pts + ((size_t)b * NN + id) * 3;
        const float* rr = rep + (size_t)bp * 3;
        pl[t][0] = q[0] - rr[0];
        pl[t][1] = q[1] - rr[1];
        pl[t][2] = q[2] - rr[2];
    }
    __syncthreads();

#pragma unroll
    for (int it = 0; it < 8; ++it) {
        int k = (t >> 6) + it * 2;
        fcat[k][32 + c64] = ftsd[((size_t)b * NN + nidx[k]) * 64 + c64];
    }

#pragma unroll
    for (int r2 = 0; r2 < 4; ++r2) {
        int e = t + 128 * r2; int k = e >> 5, j = e & 31;
        float acc = d1b[j];
        acc = fmaf(pl[k][0], d1W[j], acc);
        acc = fmaf(pl[k][1], d1W[32 + j], acc);
        acc = fmaf(pl[k][2], d1W[64 + j], acc);
        A1[k][j] = elu(acc);
    }
    __syncthreads();

#pragma unroll
    for (int r2 = 0; r2 < 4; ++r2) {
        int e = t + 128 * r2; int k = e >> 5, j = e & 31;
        float acc = d2b[j];
#pragma unroll
        for (int c = 0; c < 32; ++c) acc = fmaf(A1[k][c], d2W[c * 32 + j], acc);
        fcat[k][j] = elu(acc);
    }
    __syncthreads();

    {
        float a0 = convb[t], a1 = convb[t + 128];
#pragma unroll
        for (int c = 0; c < 3; ++c)
#pragma unroll
            for (int k = 0; k < 16; ++k) {
                float p = pl[k][c];
                const float* w = convT + (c * 16 + k) * 256 + t;
                a0 = fmaf(p, w[0],   a0);
                a1 = fmaf(p, w[128], a1);
            }
        Xm[t >> 4][t & 15] = elu(a0);
        Xm[(t >> 4) + 8][t & 15] = elu(a1);
    }
    __syncthreads();

    {
        int m = t & 15, j0 = t >> 4;
        float a0 = dw1b[t], a1 = dw1b[t + 128];
#pragma unroll
        for (int i = 0; i < 16; ++i) {
            const float* w = dw1T + i * 256 + t;
            a0 = fmaf(Xm[i][j0],     w[0],   a0);
            a1 = fmaf(Xm[i][j0 + 8], w[128], a1);
        }
        X2[j0][m] = elu(a0); X2[j0 + 8][m] = elu(a1);
    }
    __syncthreads();

    {
        int m = t & 15, j0 = t >> 4;
        float a0 = dw2b[t], a1 = dw2b[t + 128];
#pragma unroll
        for (int i = 0; i < 16; ++i) {
            const float* w = dw2T + i * 256 + t;
            a0 = fmaf(X2[i][j0],     w[0],   a0);
            a1 = fmaf(X2[i][j0 + 8], w[128], a1);
        }
        X3[j0][m] = a0; X3[j0 + 8][m] = a1;
    }
    __syncthreads();

#pragma unroll
    for (int r2 = 0; r2 < 12; ++r2) {
        int e = t + 128 * r2; int a = e & 15, c = e >> 4;
        float acc = 0.0f;
#pragma unroll
        for (int q = 0; q < 16; ++q) acc = fmaf(X3[a][q], fcat[q][c], acc);
        fX[a][c] = acc;
    }
    __syncthreads();

#pragma unroll
    for (int r2 = 0; r2 < 2; ++r2) {
        int e = t + 128 * r2;
        if (e < 192) {
            int c = e >> 1;
            float acc = sdwb[e];
#pragma unroll
            for (int k = 0; k < 16; ++k) acc = fmaf(fX[k][c], sdwT[k * 192 + e], acc);
            dsep[e] = acc;
        }
    }
    __syncthreads();

    {
        float a0 = spwb[t];
#pragma unroll 16
        for (int e2 = 0; e2 < 192; ++e2)
            a0 = fmaf(dsep[e2], spwT[e2 * 128 + t], a0);
        outp[(size_t)bp * 128 + t] = elu(a0);
    }
}

extern "C" void kernel_launch(void* const* d_in, const int* in_sizes, int n_in,
                              void* d_out, int out_size, void* d_ws, size_t ws_size,
                              hipStream_t stream) {
    const float* pts    = (const float*)d_in[0];
    const float* fts    = (const float*)d_in[1];
    const float* denseW = (const float*)d_in[2];
    const float* denseb = (const float*)d_in[3];
    const float* d1W    = (const float*)d_in[4];
    const float* d1b    = (const float*)d_in[5];
    const float* d2W    = (const float*)d_in[6];
    const float* d2b    = (const float*)d_in[7];
    const float* convW  = (const float*)d_in[8];
    const float* convb  = (const float*)d_in[9];
    const float* dw1W   = (const float*)d_in[10];
    const float* dw1b   = (const float*)d_in[11];
    const float* dw2W   = (const float*)d_in[12];
    const float* dw2b   = (const float*)d_in[13];
    const float* sdwW   = (const float*)d_in[14];
    const float* sdwb   = (const float*)d_in[15];
    const float* spwW   = (const float*)d_in[16];
    const float* spwb   = (const float*)d_in[17];

    float* rep  = (float*)d_out;                       // [B,P,3]
    float* outp = (float*)d_out + (size_t)BB * PP * 3; // [B,P,128]

    float* ftsd = (float*)d_ws;                                                // 8 MB
    int*   kidx = (int*)((char*)d_ws + (size_t)BB * NN * CIN * sizeof(float)); // 512 KB
    float* wts  = (float*)((char*)d_ws + (size_t)BB * NN * CIN * sizeof(float)
                                       + (size_t)BB * PP * KNB * sizeof(int));
    float* convT  = wts;              // 12288
    float* dw1T   = wts + 12288;      // 4096
    float* dw2T   = wts + 16384;      // 4096
    float* sdwT   = wts + 20480;      // 3072
    float* spwT   = wts + 23552;      // 24576
    float* ptsT   = wts + 48128;      // 98304 (B*3*N SoA)
    float* fstate = wts + 146432;     // 32768 (B*16*512 dist state)

    // chunk 0: FPS rounds [1,1024) + prep + dense
    mega_kernel<<<DENSE_BASE + BB * NN / 8, 512, 0, stream>>>(
        pts, rep, fts, denseW, denseb, ftsd, convW, dw1W, dw2W, sdwW, spwW,
        convT, dw1T, dw2T, sdwT, spwT, ptsT, fstate,
        d1W, d1b, d2W, d2b, convb, dw1b, dw2b, sdwb, spwb, outp,
        1, CHUNK, 0, 0);
    // chunk 1: FPS rounds [1024,2048) + consumers for points [0,1024)/batch
    mega_kernel<<<4 + 512, 512, 0, stream>>>(
        pts, rep, fts, denseW, denseb, ftsd, convW, dw1W, dw2W, sdwW, spwW,
        convT, dw1T, dw2T, sdwT, spwT, ptsT, fstate,
        d1W, d1b, d2W, d2b, convb, dw1b, dw2b, sdwb, spwb, outp,
        CHUNK, PP, 1, 0);
    // tail: points [1024,2048)/batch at full occupancy
    knn_kernel<<<1024, 256, 0, stream>>>(ptsT, rep, kidx, CHUNK);
    xconv_kernel<<<4096, 128, 0, stream>>>(pts, rep, ftsd, kidx,
                                           d1W, d1b, d2W, d2b, convT, convb,
                                           dw1T, dw1b, dw2T, dw2b,
                                           sdwT, sdwb, spwT, spwb, outp, CHUNK);
}